// Round 7
// baseline (8859.184 us; speedup 1.0000x reference)
//
#include <hip/hip_runtime.h>
#include <stdint.h>

#define TN 512
#define HN 512
#define BN 64

typedef _Float16 half8 __attribute__((ext_vector_type(8)));
typedef float floatx4 __attribute__((ext_vector_type(4)));

// ---- ws layout (bytes) ----
// xb  [512 t][4 kt][4 bt][64 lane][8 j] fp16   =  8,388,608   (x in B-frag tiles)
// h0b [512 t][16 kt][4 bt][64][8] fp16         = 33,554,432   (layer-0 h history, B-frag tiles)
// h1b same                                     = 33,554,432
// a0p [128 blk][20 kt][64 lane][8 j] fp16      =  2,621,440   (L0 A-frags: [Wih0|Whh0])
// a1p [128 blk][32 kt][64 lane][8 j] fp16      =  4,194,304   (L1 A-frags: [Wih1|Whh1])
// f0  [4 bt][128 blk] u32 epoch flags          =      2,048
// f1  [4 bt][128 blk] u32 epoch flags          =      2,048
#define XB_OFF  (0ULL)
#define H0_OFF  (8388608ULL)
#define H1_OFF  (41943040ULL)
#define A0_OFF  (75497472ULL)
#define A1_OFF  (78118912ULL)
#define F0_OFF  (82313216ULL)
#define F1_OFF  (82315264ULL)

__device__ __forceinline__ float sigm(float x) { return 1.f / (1.f + __expf(-x)); }
__device__ __forceinline__ float tanh_(float x) {
    float e = __expf(2.f * x);
    return 1.f - 2.f / (e + 1.f);
}

// Spin until all 128 words of this flag set reach `target` (epoch compare).
// BOUNDED: breaks after ~512 iterations (~150-300 us) so a visibility stall
// becomes a wrong-answer diagnosis instead of a dead container. Expected
// steady-state wait is <1 us, so the cap never fires when sync is healthy.
__device__ __forceinline__ void wait_set(const uint32_t* f, uint32_t target, int l) {
    for (int it = 0; it < 512; ++it) {
        uint32_t a = __hip_atomic_load(f + l,      __ATOMIC_RELAXED, __HIP_MEMORY_SCOPE_AGENT);
        uint32_t b = __hip_atomic_load(f + 64 + l, __ATOMIC_RELAXED, __HIP_MEMORY_SCOPE_AGENT);
        if (__all(a >= target && b >= target)) break;
        __builtin_amdgcn_s_sleep(8);
    }
    __atomic_signal_fence(__ATOMIC_SEQ_CST);
}

// x[b][t][d] fp32 -> B-frag tiles: xb[t][kt][bt][lane][j]
__global__ __launch_bounds__(256) void pack_x(const float* __restrict__ x, uint32_t* __restrict__ xb) {
    const int bx = blockIdx.x;                 // t*16 + kt*4 + bt
    const int t = bx >> 4, kt = (bx >> 2) & 3, bt = bx & 3;
    const int tid = threadIdx.x;
    const int jp = tid & 3, lane = tid >> 2;
    const int n = bt * 16 + (lane & 15);
    const int k = kt * 32 + (lane >> 4) * 8 + jp * 2;
    const float* src = x + ((size_t)n * TN + t) * 128 + k;
    union { _Float16 h[2]; uint32_t u; } z;
    z.h[0] = (_Float16)src[0]; z.h[1] = (_Float16)src[1];
    xb[((size_t)bx * 64 + lane) * 4 + jp] = z.u;
}

// W -> A-frags, rows ordered r = ui*4 + g so C quad = unit, C reg = gate.
__global__ __launch_bounds__(256) void pack_a(const float* __restrict__ Wih, const float* __restrict__ Whh,
                                              int kin, int nkt, uint32_t* __restrict__ ap) {
    const int bx = blockIdx.x;                 // b*nkt + kt
    const int b = bx / nkt, kt = bx - b * nkt;
    const int tid = threadIdx.x;
    const int jp = tid & 3, lane = tid >> 2;
    const int r = lane & 15, quad = lane >> 4;
    const int k = kt * 32 + quad * 8 + jp * 2;
    const int grow = (r & 3) * HN + b * 4 + (r >> 2);
    float v0, v1;
    if (k < kin) { v0 = Wih[(size_t)grow * kin + k];       v1 = Wih[(size_t)grow * kin + k + 1]; }
    else         { v0 = Whh[(size_t)grow * HN + k - kin];  v1 = Whh[(size_t)grow * HN + k - kin + 1]; }
    union { _Float16 h[2]; uint32_t u; } z;
    z.h[0] = (_Float16)v0; z.h[1] = (_Float16)v1;
    ap[((size_t)bx * 64 + lane) * 4 + jp] = z.u;
}

// Persistent kernel: 256 blocks x 512 threads, 1 block/CU.
// Blocks 0-127: layer 0. Blocks 128-255: layer 1. Wave w: bt=w&3, kh=w>>2.
// kh=0 waves: local/early inputs (x for L0, h0[s] for L1) + cell update + publish.
// kh=1 waves: the recurrent input (h0[s-1] for L0, h1[s-1] for L1).
// One __syncthreads per step; red[] double-buffered by parity.
__global__ __launch_bounds__(512, 2) void lstm_mfma(
    const uint4* __restrict__ xb, uint4* h0b, uint4* h1b,
    const uint4* __restrict__ a0p, const uint4* __restrict__ a1p,
    const float* __restrict__ bih0, const float* __restrict__ bhh0,
    const float* __restrict__ bih1, const float* __restrict__ bhh1,
    uint32_t* f0, uint32_t* f1)
{
    __shared__ float red[2][4][64][4];         // [parity][bt][lane][gate]
    const int tid  = threadIdx.x;
    const int l    = tid & 63;
    const int w    = __builtin_amdgcn_readfirstlane(tid >> 6);
    const int bt   = w & 3, kh = w >> 2;
    const int quad = l >> 4, nl = l & 15;
    const int blk  = blockIdx.x;
    const bool isL0 = (blk < 128);
    const int b    = isL0 ? blk : blk - 128;
    const int u0   = b * 4;

    float bias[4];
    {
        const float* bi = isL0 ? bih0 : bih1;
        const float* bh = isL0 ? bhh0 : bhh1;
#pragma unroll
        for (int g = 0; g < 4; ++g) {
            int grow = g * HN + u0 + quad;
            bias[g] = bi[grow] + bh[grow];
        }
    }
    float cst = 0.f;
    const int ktp = u0 >> 5, kqp = (u0 >> 3) & 3, jb = u0 & 7;

    if (isL0) {
        if (kh == 0) {
            half8 A[4];
            const uint4* ap = a0p + ((size_t)b * 20) * 64 + l;
#pragma unroll
            for (int kk = 0; kk < 4; ++kk) A[kk] = __builtin_bit_cast(half8, ap[(size_t)kk * 64]);
            uint32_t* fme = f0 + bt * 128 + blk;
            for (int s = 0; s < TN; ++s) {
                floatx4 acc = {0.f,0.f,0.f,0.f};
#pragma unroll
                for (int kk = 0; kk < 4; ++kk) {
                    uint4 bv = xb[(((size_t)s * 4 + kk) * 4 + bt) * 64 + l];
                    acc = __builtin_amdgcn_mfma_f32_16x16x32_f16(A[kk], __builtin_bit_cast(half8, bv), acc, 0, 0, 0);
                }
                __syncthreads();
                float gi = acc[0] + red[s & 1][bt][l][0] + bias[0];
                float gf = acc[1] + red[s & 1][bt][l][1] + bias[1];
                float gg = acc[2] + red[s & 1][bt][l][2] + bias[2];
                float go = acc[3] + red[s & 1][bt][l][3] + bias[3];
                float c = sigm(gf) * cst + sigm(gi) * tanh_(gg);
                cst = c;
                float h = sigm(go) * tanh_(c);
                union { _Float16 hf; uint16_t u; } cv; cv.hf = (_Float16)h;
                uint32_t myu = cv.u;
                uint32_t a32 = myu | (((uint32_t)__shfl_xor((int)myu, 16)) << 16);
                uint32_t h32 = (uint32_t)__shfl_xor((int)a32, 32);
                if (quad == 0) {
                    uint64_t val = (uint64_t)a32 | ((uint64_t)h32 << 32);
                    uint64_t* dst = (uint64_t*)((char*)h0b +
                        ((((size_t)s * 16 + ktp) * 4 + bt) * 1024 + (kqp * 16 + nl) * 16 + jb * 2));
                    __hip_atomic_store(dst, val, __ATOMIC_RELAXED, __HIP_MEMORY_SCOPE_AGENT);
                }
                if (l == 0)
                    __hip_atomic_store(fme, (uint32_t)(s + 1), __ATOMIC_RELEASE, __HIP_MEMORY_SCOPE_AGENT);
            }
        } else {  // kh == 1: h0[s-1] recurrence, 16 tiles
            half8 A[16];
            const uint4* ap = a0p + ((size_t)b * 20 + 4) * 64 + l;
#pragma unroll
            for (int kk = 0; kk < 16; ++kk) A[kk] = __builtin_bit_cast(half8, ap[(size_t)kk * 64]);
            for (int s = 0; s < TN; ++s) {
                floatx4 ca = {0.f,0.f,0.f,0.f}, cb = {0.f,0.f,0.f,0.f};
                if (s > 0) {
                    wait_set(f0 + bt * 128, (uint32_t)s, l);
#pragma unroll
                    for (int kk = 0; kk < 16; ++kk) {
                        uint4 bv = h0b[(((size_t)(s - 1) * 16 + kk) * 4 + bt) * 64 + l];
                        half8 B = __builtin_bit_cast(half8, bv);
                        if (kk & 1) cb = __builtin_amdgcn_mfma_f32_16x16x32_f16(A[kk], B, cb, 0, 0, 0);
                        else        ca = __builtin_amdgcn_mfma_f32_16x16x32_f16(A[kk], B, ca, 0, 0, 0);
                    }
                }
                floatx4 acc = ca + cb;
#pragma unroll
                for (int g = 0; g < 4; ++g) red[s & 1][bt][l][g] = acc[g];
                __syncthreads();
            }
        }
    } else {
        if (kh == 0) {  // h0[s] feed (off critical path; L0 runs ahead) + cell + publish
            half8 A[16];
            const uint4* ap = a1p + ((size_t)b * 32) * 64 + l;
#pragma unroll
            for (int kk = 0; kk < 16; ++kk) A[kk] = __builtin_bit_cast(half8, ap[(size_t)kk * 64]);
            uint32_t* fme = f1 + bt * 128 + b;
            for (int s = 0; s < TN; ++s) {
                wait_set(f0 + bt * 128, (uint32_t)(s + 1), l);
                floatx4 ca = {0.f,0.f,0.f,0.f}, cb = {0.f,0.f,0.f,0.f};
#pragma unroll
                for (int kk = 0; kk < 16; ++kk) {
                    uint4 bv = h0b[(((size_t)s * 16 + kk) * 4 + bt) * 64 + l];
                    half8 B = __builtin_bit_cast(half8, bv);
                    if (kk & 1) cb = __builtin_amdgcn_mfma_f32_16x16x32_f16(A[kk], B, cb, 0, 0, 0);
                    else        ca = __builtin_amdgcn_mfma_f32_16x16x32_f16(A[kk], B, ca, 0, 0, 0);
                }
                floatx4 acc = ca + cb;
                __syncthreads();
                float gi = acc[0] + red[s & 1][bt][l][0] + bias[0];
                float gf = acc[1] + red[s & 1][bt][l][1] + bias[1];
                float gg = acc[2] + red[s & 1][bt][l][2] + bias[2];
                float go = acc[3] + red[s & 1][bt][l][3] + bias[3];
                float c = sigm(gf) * cst + sigm(gi) * tanh_(gg);
                cst = c;
                float h = sigm(go) * tanh_(c);
                union { _Float16 hf; uint16_t u; } cv; cv.hf = (_Float16)h;
                uint32_t myu = cv.u;
                uint32_t a32 = myu | (((uint32_t)__shfl_xor((int)myu, 16)) << 16);
                uint32_t h32 = (uint32_t)__shfl_xor((int)a32, 32);
                if (quad == 0) {
                    uint64_t val = (uint64_t)a32 | ((uint64_t)h32 << 32);
                    uint64_t* dst = (uint64_t*)((char*)h1b +
                        ((((size_t)s * 16 + ktp) * 4 + bt) * 1024 + (kqp * 16 + nl) * 16 + jb * 2));
                    __hip_atomic_store(dst, val, __ATOMIC_RELAXED, __HIP_MEMORY_SCOPE_AGENT);
                }
                if (l == 0)
                    __hip_atomic_store(fme, (uint32_t)(s + 1), __ATOMIC_RELEASE, __HIP_MEMORY_SCOPE_AGENT);
            }
        } else {  // kh == 1: h1[s-1] recurrence
            half8 A[16];
            const uint4* ap = a1p + ((size_t)b * 32 + 16) * 64 + l;
#pragma unroll
            for (int kk = 0; kk < 16; ++kk) A[kk] = __builtin_bit_cast(half8, ap[(size_t)kk * 64]);
            for (int s = 0; s < TN; ++s) {
                floatx4 ca = {0.f,0.f,0.f,0.f}, cb = {0.f,0.f,0.f,0.f};
                if (s > 0) {
                    wait_set(f1 + bt * 128, (uint32_t)s, l);
#pragma unroll
                    for (int kk = 0; kk < 16; ++kk) {
                        uint4 bv = h1b[(((size_t)(s - 1) * 16 + kk) * 4 + bt) * 64 + l];
                        half8 B = __builtin_bit_cast(half8, bv);
                        if (kk & 1) cb = __builtin_amdgcn_mfma_f32_16x16x32_f16(A[kk], B, cb, 0, 0, 0);
                        else        ca = __builtin_amdgcn_mfma_f32_16x16x32_f16(A[kk], B, ca, 0, 0, 0);
                    }
                }
                floatx4 acc = ca + cb;
#pragma unroll
                for (int g = 0; g < 4; ++g) red[s & 1][bt][l][g] = acc[g];
                __syncthreads();
            }
        }
    }
}

// out[n][o] = sum_k h1[T-1][k][n] * Wfc[o][k] + bfc[o]
__global__ __launch_bounds__(256) void fc_kernel(const uint16_t* __restrict__ h1b,
                                                 const float* __restrict__ Wfc,
                                                 const float* __restrict__ bfc,
                                                 float* __restrict__ out) {
    const int o = blockIdx.x, tid = threadIdx.x;
    const int bb = tid & 63, kq = tid >> 6;
    float p = 0.f;
    for (int k = kq * 128; k < kq * 128 + 128; ++k) {
        size_t idx = ((((size_t)511 * 16 + (k >> 5)) * 4 + (bb >> 4)) * 64
                      + ((k >> 3) & 3) * 16 + (bb & 15)) * 8 + (k & 7);
        _Float16 hv = ((const _Float16*)h1b)[idx];
        p = fmaf((float)hv, Wfc[(size_t)o * HN + k], p);
    }
    __shared__ float red[4][64];
    red[kq][bb] = p;
    __syncthreads();
    if (tid < 64)
        out[(size_t)tid * 128 + o] = bfc[o] + red[0][tid] + red[1][tid] + red[2][tid] + red[3][tid];
}

extern "C" void kernel_launch(void* const* d_in, const int* in_sizes, int n_in,
                              void* d_out, int out_size, void* d_ws, size_t ws_size,
                              hipStream_t stream) {
    const float* x    = (const float*)d_in[0];
    const float* Wih0 = (const float*)d_in[1];
    const float* Whh0 = (const float*)d_in[2];
    const float* bih0 = (const float*)d_in[3];
    const float* bhh0 = (const float*)d_in[4];
    const float* Wih1 = (const float*)d_in[5];
    const float* Whh1 = (const float*)d_in[6];
    const float* bih1 = (const float*)d_in[7];
    const float* bhh1 = (const float*)d_in[8];
    const float* Wfc  = (const float*)d_in[9];
    const float* bfc  = (const float*)d_in[10];

    char* ws = (char*)d_ws;
    uint32_t* xb  = (uint32_t*)(ws + XB_OFF);
    uint4*    h0b = (uint4*)(ws + H0_OFF);
    uint4*    h1b = (uint4*)(ws + H1_OFF);
    uint32_t* a0p = (uint32_t*)(ws + A0_OFF);
    uint32_t* a1p = (uint32_t*)(ws + A1_OFF);
    uint32_t* f0  = (uint32_t*)(ws + F0_OFF);
    uint32_t* f1  = (uint32_t*)(ws + F1_OFF);

    hipMemsetAsync(f0, 0, 4096, stream);   // f0 + f1 (epoch flags start at 0)

    hipLaunchKernelGGL(pack_x, dim3(TN * 16), dim3(256), 0, stream, x, xb);
    hipLaunchKernelGGL(pack_a, dim3(128 * 20), dim3(256), 0, stream, Wih0, Whh0, 128, 20, a0p);
    hipLaunchKernelGGL(pack_a, dim3(128 * 32), dim3(256), 0, stream, Wih1, Whh1, 512, 32, a1p);

    const uint4* xbc = (const uint4*)xb;
    const uint4* a0c = (const uint4*)a0p;
    const uint4* a1c = (const uint4*)a1p;
    void* args[] = { &xbc, &h0b, &h1b, &a0c, &a1c,
                     &bih0, &bhh0, &bih1, &bhh1, &f0, &f1 };
    hipLaunchCooperativeKernel((void*)lstm_mfma, dim3(256), dim3(512), args, 0, stream);

    hipLaunchKernelGGL(fc_kernel, dim3(128), dim3(256), 0, stream,
                       (const uint16_t*)h1b, Wfc, bfc, (float*)d_out);
}

// Round 8
// 4696.326 us; speedup vs baseline: 1.8864x; 1.8864x over previous
//
#include <hip/hip_runtime.h>
#include <stdint.h>

#define TN 512
#define HN 512
#define BN 64

typedef _Float16 half8 __attribute__((ext_vector_type(8)));
typedef float floatx4 __attribute__((ext_vector_type(4)));

// ---- ws layout (bytes) ----
// xb  [512 t][4 kt][4 bt][64 lane][8 j] fp16   =  8,388,608
// h0b [512 t][16 kt][4 bt][64][8] fp16         = 33,554,432
// h1b same                                     = 33,554,432
// a0p [32 b][4 rt][20 kt][64][8] fp16          =  2,621,440
// a1p [32 b][4 rt][32 kt][64][8] fp16          =  4,194,304
// f0  [512 s][32 blk] u32 (128B line per step) =     65,536
// f1  same                                     =     65,536
#define XB_OFF  (0ULL)
#define H0_OFF  (8388608ULL)
#define H1_OFF  (41943040ULL)
#define A0_OFF  (75497472ULL)
#define A1_OFF  (78118912ULL)
#define F0_OFF  (82313216ULL)
#define F1_OFF  (82378752ULL)

__device__ __forceinline__ float sigm(float x) { return 1.f / (1.f + __expf(-x)); }
__device__ __forceinline__ float tanh_(float x) {
    float e = __expf(2.f * x);
    return 1.f - 2.f / (e + 1.f);
}

// x[b][t][d] fp32 -> B-frag tiles xb[t][kt][bt][lane][j]  (verified R4-R7)
__global__ __launch_bounds__(256) void pack_x(const float* __restrict__ x, uint32_t* __restrict__ xb) {
    const int bx = blockIdx.x;                 // t*16 + kt*4 + bt
    const int t = bx >> 4, kt = (bx >> 2) & 3, bt = bx & 3;
    const int tid = threadIdx.x;
    const int jp = tid & 3, lane = tid >> 2;
    const int n = bt * 16 + (lane & 15);
    const int k = kt * 32 + (lane >> 4) * 8 + jp * 2;
    const float* src = x + ((size_t)n * TN + t) * 128 + k;
    union { _Float16 h[2]; uint32_t u; } z;
    z.h[0] = (_Float16)src[0]; z.h[1] = (_Float16)src[1];
    xb[((size_t)bx * 64 + lane) * 4 + jp] = z.u;
}

// W -> A-frags for 16-unit blocks. Local row r = ui*4 + g (ui 0..15, g 0..3) so a
// 16x16 C tile (rt) gives lane(quad,nl): unit = rt*4+quad, gates = the 4 C regs.
// ap[((b*4+rt)*nkt + kt)][lane][j]; grow = g*512 + b*16 + ui; k = kt*32 + quad*8 + j.
__global__ __launch_bounds__(256) void pack_a(const float* __restrict__ Wih, const float* __restrict__ Whh,
                                              int kin, int nkt, uint32_t* __restrict__ ap) {
    const int bx = blockIdx.x;                 // b*(4*nkt) + rt*nkt + kt
    const int kt = bx % nkt;
    const int rt = (bx / nkt) & 3;
    const int b  = bx / (nkt * 4);
    const int tid = threadIdx.x;
    const int jp = tid & 3, lane = tid >> 2;
    const int nl = lane & 15, quad = lane >> 4;
    const int r = rt * 16 + nl;
    const int k = kt * 32 + quad * 8 + jp * 2;
    const int grow = (r & 3) * 512 + b * 16 + (r >> 2);
    float v0, v1;
    if (k < kin) { v0 = Wih[(size_t)grow * kin + k];       v1 = Wih[(size_t)grow * kin + k + 1]; }
    else         { v0 = Whh[(size_t)grow * 512 + k - kin]; v1 = Whh[(size_t)grow * 512 + k - kin + 1]; }
    union { _Float16 h[2]; uint32_t u; } z;
    z.h[0] = (_Float16)v0; z.h[1] = (_Float16)v1;
    ap[(size_t)bx * 256 + lane * 4 + jp] = z.u;
}

// One LSTM layer on 32 blocks; block owns units u0=16b..16b+15 (all 64 gate rows,
// full batch). Wave w=(p=w&1,q=w>>1): bt in {2p,2p+1}, ktiles [q*NQ, q*NQ+NQ).
// B-frag loaded once per (bt,kt), reused over 4 row-tiles in-register.
// 4-way k-group reduction via LDS; q==0 waves do cell update + publish.
template<int NQ, int NSRC0>
__device__ __forceinline__ void run_layer(
    int b, int p, int q, int l, int quad, int nl,
    const uint4* __restrict__ src0, const uint4* __restrict__ src1,
    const uint4* __restrict__ apL, uint4* hout,
    const float* __restrict__ bi, const float* __restrict__ bh,
    uint32_t* fout, const uint32_t* f_in0, int t0, const uint32_t* f_in1,
    float4 (*parts)[8][64])
{
    constexpr int NKT = 4 * NQ;
    const int u0 = b * 16;

    half8 A[4][NQ];
#pragma unroll
    for (int rt = 0; rt < 4; ++rt)
#pragma unroll
        for (int kk = 0; kk < NQ; ++kk)
            A[rt][kk] = __builtin_bit_cast(half8,
                apL[(((size_t)b * 4 + rt) * NKT + q * NQ + kk) * 64 + l]);

    float bias[4][4];
    float cst[2][4];
    if (q == 0) {
#pragma unroll
        for (int rt = 0; rt < 4; ++rt)
#pragma unroll
            for (int g = 0; g < 4; ++g) {
                int grow = g * 512 + u0 + rt * 4 + quad;
                bias[rt][g] = bi[grow] + bh[grow];
            }
#pragma unroll
        for (int i2 = 0; i2 < 2; ++i2)
#pragma unroll
            for (int rt = 0; rt < 4; ++rt) cst[i2][rt] = 0.f;
    }

    for (int s = 0; s < TN; ++s) {
        // ---- poll (wave 0 only; barrier broadcasts readiness) ----
        if (p == 0 && q == 0) {
            const uint32_t* fa = (s + t0 >= 0) ? f_in0 + (size_t)(s + t0) * 32 : nullptr;
            const uint32_t* fb = (f_in1 && s > 0) ? f_in1 + (size_t)(s - 1) * 32 : nullptr;
            if (fa || fb) {
                for (int it = 0; it < 768; ++it) {   // bounded: ~0.27 ms worst case
                    uint32_t a  = fa ? __hip_atomic_load(fa + (l & 31), __ATOMIC_RELAXED, __HIP_MEMORY_SCOPE_AGENT) : 1u;
                    uint32_t b2 = fb ? __hip_atomic_load(fb + (l & 31), __ATOMIC_RELAXED, __HIP_MEMORY_SCOPE_AGENT) : 1u;
                    if (__all(a != 0u && b2 != 0u)) break;
                    __builtin_amdgcn_s_sleep(2);
                }
            }
            __atomic_signal_fence(__ATOMIC_SEQ_CST);
        }
        __syncthreads();                              // B1: inputs ready

        // ---- MFMA: B loaded once per (bt,kt), reused over 4 rt ----
        floatx4 acc[2][4];
#pragma unroll
        for (int bi2 = 0; bi2 < 2; ++bi2)
#pragma unroll
            for (int rt = 0; rt < 4; ++rt) acc[bi2][rt] = floatx4{0.f, 0.f, 0.f, 0.f};

#pragma unroll
        for (int kk = 0; kk < NQ; ++kk) {
            const int kt = q * NQ + kk;
#pragma unroll
            for (int bi2 = 0; bi2 < 2; ++bi2) {
                const int bt = 2 * p + bi2;
                uint4 bv; bool have = true;
                if (kt < NSRC0)      bv = src0[(((size_t)s * NSRC0 + kt) * 4 + bt) * 64 + l];
                else if (s > 0)      bv = src1[(((size_t)(s - 1) * 16 + (kt - NSRC0)) * 4 + bt) * 64 + l];
                else                 have = false;
                if (have) {
                    half8 B = __builtin_bit_cast(half8, bv);
#pragma unroll
                    for (int rt = 0; rt < 4; ++rt)
                        acc[bi2][rt] = __builtin_amdgcn_mfma_f32_16x16x32_f16(A[rt][kk], B, acc[bi2][rt], 0, 0, 0);
                }
            }
        }

        if (q > 0) {
            const int wslot = (q - 1) * 2 + p;        // 0..5
#pragma unroll
            for (int bi2 = 0; bi2 < 2; ++bi2)
#pragma unroll
                for (int rt = 0; rt < 4; ++rt) {
                    float4 v;
                    v.x = acc[bi2][rt][0]; v.y = acc[bi2][rt][1];
                    v.z = acc[bi2][rt][2]; v.w = acc[bi2][rt][3];
                    parts[wslot][bi2 * 4 + rt][l] = v;
                }
        }
        __syncthreads();                              // B2: parts visible

        // ---- reduce + cell + publish (q==0 waves) ----
        if (q == 0) {
#pragma unroll
            for (int bi2 = 0; bi2 < 2; ++bi2) {
                const int bt = 2 * p + bi2;
#pragma unroll
                for (int rt = 0; rt < 4; ++rt) {
                    const int ti = bi2 * 4 + rt;
                    float4 v0 = parts[p][ti][l], v1 = parts[2 + p][ti][l], v2 = parts[4 + p][ti][l];
                    float gi = acc[bi2][rt][0] + v0.x + v1.x + v2.x + bias[rt][0];
                    float gf = acc[bi2][rt][1] + v0.y + v1.y + v2.y + bias[rt][1];
                    float gg = acc[bi2][rt][2] + v0.z + v1.z + v2.z + bias[rt][2];
                    float go = acc[bi2][rt][3] + v0.w + v1.w + v2.w + bias[rt][3];
                    float c = sigm(gf) * cst[bi2][rt] + sigm(gi) * tanh_(gg);
                    cst[bi2][rt] = c;
                    float h = sigm(go) * tanh_(c);
                    union { _Float16 hf; uint16_t u; } cv; cv.hf = (_Float16)h;
                    uint32_t myu = cv.u;
                    uint32_t a32 = myu | (((uint32_t)__shfl_xor((int)myu, 16)) << 16);
                    uint32_t h32 = (uint32_t)__shfl_xor((int)a32, 32);
                    if (quad == 0) {                  // 4 units -> one aligned 8B store
                        const int kt_g = (u0 + rt * 4) >> 5;
                        const int base = (u0 & 31) + rt * 4;   // 0,4,..,28
                        uint64_t val = (uint64_t)a32 | ((uint64_t)h32 << 32);
                        uint64_t* dst = (uint64_t*)((char*)hout +
                            ((((size_t)s * 16 + kt_g) * 4 + bt) * 64 + ((base >> 3) * 16 + nl)) * 16
                            + (base & 7) * 2);
                        __hip_atomic_store(dst, val, __ATOMIC_RELAXED, __HIP_MEMORY_SCOPE_AGENT);
                    }
                }
            }
        }
        __syncthreads();                              // B3: all h stores drained (vmcnt0/wave)
        if (p == 0 && q == 0 && l == 0)
            __hip_atomic_store(fout + (size_t)s * 32 + b, 1u, __ATOMIC_RELEASE, __HIP_MEMORY_SCOPE_AGENT);
    }
}

// 64 blocks x 512 threads, 1 block/CU. Blocks 0-31: layer 0; 32-63: layer 1.
__global__ __launch_bounds__(512, 2) void lstm2(
    const uint4* __restrict__ xb, uint4* h0b, uint4* h1b,
    const uint4* __restrict__ a0p, const uint4* __restrict__ a1p,
    const float* __restrict__ bih0, const float* __restrict__ bhh0,
    const float* __restrict__ bih1, const float* __restrict__ bhh1,
    uint32_t* f0, uint32_t* f1)
{
    __shared__ float4 parts[6][8][64];                // 48 KB
    const int tid = threadIdx.x;
    const int l = tid & 63;
    const int w = __builtin_amdgcn_readfirstlane(tid >> 6);
    const int p = w & 1, q = w >> 1;
    const int quad = l >> 4, nl = l & 15;
    const int blk = blockIdx.x;
    if (blk < 32)
        run_layer<5, 4>(blk, p, q, l, quad, nl, xb, h0b, a0p, h0b, bih0, bhh0,
                        f0, f0, -1, nullptr, parts);
    else
        run_layer<8, 16>(blk - 32, p, q, l, quad, nl, h0b, h1b, a1p, h1b, bih1, bhh1,
                         f1, f0, 0, f1, parts);
}

// out[n][o] = sum_k h1[T-1][k][n] * Wfc[o][k] + bfc[o]  (B-frag tile layout)
__global__ __launch_bounds__(256) void fc_kernel(const uint16_t* __restrict__ h1b,
                                                 const float* __restrict__ Wfc,
                                                 const float* __restrict__ bfc,
                                                 float* __restrict__ out) {
    const int o = blockIdx.x, tid = threadIdx.x;
    const int bb = tid & 63, kq = tid >> 6;
    float p = 0.f;
    for (int k = kq * 128; k < kq * 128 + 128; ++k) {
        size_t idx = ((((size_t)511 * 16 + (k >> 5)) * 4 + (bb >> 4)) * 64
                      + ((k >> 3) & 3) * 16 + (bb & 15)) * 8 + (k & 7);
        _Float16 hv = ((const _Float16*)h1b)[idx];
        p = fmaf((float)hv, Wfc[(size_t)o * HN + k], p);
    }
    __shared__ float red[4][64];
    red[kq][bb] = p;
    __syncthreads();
    if (tid < 64)
        out[(size_t)tid * 128 + o] = bfc[o] + red[0][tid] + red[1][tid] + red[2][tid] + red[3][tid];
}

extern "C" void kernel_launch(void* const* d_in, const int* in_sizes, int n_in,
                              void* d_out, int out_size, void* d_ws, size_t ws_size,
                              hipStream_t stream) {
    const float* x    = (const float*)d_in[0];
    const float* Wih0 = (const float*)d_in[1];
    const float* Whh0 = (const float*)d_in[2];
    const float* bih0 = (const float*)d_in[3];
    const float* bhh0 = (const float*)d_in[4];
    const float* Wih1 = (const float*)d_in[5];
    const float* Whh1 = (const float*)d_in[6];
    const float* bih1 = (const float*)d_in[7];
    const float* bhh1 = (const float*)d_in[8];
    const float* Wfc  = (const float*)d_in[9];
    const float* bfc  = (const float*)d_in[10];

    char* ws = (char*)d_ws;
    uint32_t* xb  = (uint32_t*)(ws + XB_OFF);
    uint4*    h0b = (uint4*)(ws + H0_OFF);
    uint4*    h1b = (uint4*)(ws + H1_OFF);
    uint32_t* a0p = (uint32_t*)(ws + A0_OFF);
    uint32_t* a1p = (uint32_t*)(ws + A1_OFF);
    uint32_t* f0  = (uint32_t*)(ws + F0_OFF);
    uint32_t* f1  = (uint32_t*)(ws + F1_OFF);

    hipMemsetAsync(f0, 0, 131072, stream);            // f0 + f1 (adjacent)

    hipLaunchKernelGGL(pack_x, dim3(TN * 16), dim3(256), 0, stream, x, xb);
    hipLaunchKernelGGL(pack_a, dim3(32 * 4 * 20), dim3(256), 0, stream, Wih0, Whh0, 128, 20, a0p);
    hipLaunchKernelGGL(pack_a, dim3(32 * 4 * 32), dim3(256), 0, stream, Wih1, Whh1, 512, 32, a1p);

    const uint4* xbc = (const uint4*)xb;
    const uint4* a0c = (const uint4*)a0p;
    const uint4* a1c = (const uint4*)a1p;
    void* args[] = { &xbc, &h0b, &h1b, &a0c, &a1c,
                     &bih0, &bhh0, &bih1, &bhh1, &f0, &f1 };
    hipLaunchCooperativeKernel((void*)lstm2, dim3(64), dim3(512), args, 0, stream);

    hipLaunchKernelGGL(fc_kernel, dim3(128), dim3(256), 0, stream,
                       (const uint16_t*)h1b, Wfc, bfc, (float*)d_out);
}